// Round 6
// baseline (148.792 us; speedup 1.0000x reference)
//
#include <hip/hip_runtime.h>
#include <hip/hip_bf16.h>

// C = triu( triu(A) @ triu(B) ), N=4096, fp32 in/out.
// Split-K bf16-MFMA: each upper tile (bi,bj) with L = bj-bi+1 k-tiles of 128
// is split into ceil(L/4) sub-blocks (<=16 K-steps each) -> 1704 uniform
// blocks (~6.7/CU) instead of 528 blocks with a 128-step serial tail.
// Kernel 1 zeroes C (lower-tri poison + atomic base); kernel 2 accumulates
// partials with native fp32 atomics (no inter-block ordering assumed).

#define NDIM 4096
#define BM 128
#define BN 128
#define BK 32
#define NBLK (NDIM / BM)                  // 32
#define CHUNK_KT 4                        // k-tiles of 128 per sub-block
#define NSUB 1704                         // sum over L of (33-L)*ceil(L/4)
#define LSTR 80                           // LDS row stride (64B data + 16B pad)

typedef __attribute__((ext_vector_type(8))) short short8;
typedef __attribute__((ext_vector_type(4))) float floatx4;

__device__ __forceinline__ int loff(int row, int kb) {
    return row * LSTR + kb;
}

// packed fp32x2 -> bf16x2 (RNE) -- compiler emits v_cvt_pk_bf16_f32
__device__ __forceinline__ unsigned pkbf(float a, float b) {
    __hip_bfloat162 h = __float22bfloat162_rn(make_float2(a, b));
    unsigned r;
    __builtin_memcpy(&r, &h, sizeof(r));
    return r;
}

__global__ __launch_bounds__(256) void zero_c_kernel(float* __restrict__ C) {
    const float4 z = make_float4(0.f, 0.f, 0.f, 0.f);
    const size_t total = (size_t)NDIM * NDIM / 4;  // float4 count
    for (size_t i = blockIdx.x * 256 + threadIdx.x; i < total;
         i += (size_t)gridDim.x * 256)
        reinterpret_cast<float4*>(C)[i] = z;
}

__global__ __launch_bounds__(256) void trimm_split_kernel(
    const float* __restrict__ A, const float* __restrict__ B,
    float* __restrict__ C) {
    const int tid = threadIdx.x;

    // ---- decode sub-block id -> (bi, bj, chunk) ----
    int bi, bj, ch;
    {
        int r = blockIdx.x;
        int L = NBLK;
        for (;;) {
            const int cpt = (L + 3) >> 2;            // chunks per tile
            const int cnt = (NBLK + 1 - L) * cpt;    // sub-blocks at this L
            if (r < cnt) {
                bi = r / cpt;
                ch = r - bi * cpt;
                bj = bi + L - 1;
                break;
            }
            r -= cnt;
            --L;
        }
    }

    const int row0 = bi * BM;
    const int col0 = bj * BN;
    const int kstart = row0 + ch * (CHUNK_KT * 128);
    const int kend = min(col0 + BN, kstart + CHUNK_KT * 128);

    __shared__ __align__(16) char lAs[BM * LSTR];  // 10 KB [row][k] bf16
    __shared__ __align__(16) char lBs[BN * LSTR];  // 10 KB [col][k] bf16 (B^T)

    floatx4 acc[4][4];
    const floatx4 fz = {0.f, 0.f, 0.f, 0.f};
#pragma unroll
    for (int m = 0; m < 4; ++m)
#pragma unroll
        for (int n = 0; n < 4; ++n) acc[m][n] = fz;

    const int wv = tid >> 6;
    const int wr = (wv >> 1) * 64;
    const int wc = (wv & 1) * 64;
    const int lane = tid & 63;
    const int fr = lane & 15;
    const int kb = (lane >> 4) * 16;

    // A staging geometry: thread owns 4 float4 chunks (row ar[j], float kq aq[j])
    int ar[4], aq[4];
#pragma unroll
    for (int j = 0; j < 4; ++j) {
        const int f = tid + 256 * j;
        ar[j] = f >> 3;
        aq[j] = (f & 7) * 4;
    }
    // B staging geometry: thread owns column bn, k-half bkh
    const int bn = tid & 127;
    const int bkh = (tid >> 7) * 16;

    float4 pa[4];
    float pb[16];

    // ---- prologue: prefetch first tile into registers ----
#pragma unroll
    for (int j = 0; j < 4; ++j)
        pa[j] = *reinterpret_cast<const float4*>(
            &A[(size_t)(row0 + ar[j]) * NDIM + kstart + aq[j]]);
#pragma unroll
    for (int kk = 0; kk < 16; ++kk)
        pb[kk] = B[(size_t)(kstart + bkh + kk) * NDIM + col0 + bn];

    for (int kt = kstart; kt < kend; kt += BK) {
        // ---- phase 1: convert + ds_write tile t from registers ----
#pragma unroll
        for (int j = 0; j < 4; ++j) {
            uint2 w;
            w.x = pkbf(pa[j].x, pa[j].y);
            w.y = pkbf(pa[j].z, pa[j].w);
            *reinterpret_cast<uint2*>(lAs + loff(ar[j], aq[j] * 2)) = w;
        }
        {
            uint4 w0, w1;
            w0.x = pkbf(pb[0], pb[1]);
            w0.y = pkbf(pb[2], pb[3]);
            w0.z = pkbf(pb[4], pb[5]);
            w0.w = pkbf(pb[6], pb[7]);
            w1.x = pkbf(pb[8], pb[9]);
            w1.y = pkbf(pb[10], pb[11]);
            w1.z = pkbf(pb[12], pb[13]);
            w1.w = pkbf(pb[14], pb[15]);
            *reinterpret_cast<uint4*>(lBs + loff(bn, bkh * 2)) = w0;
            *reinterpret_cast<uint4*>(lBs + loff(bn, bkh * 2 + 16)) = w1;
        }
        __syncthreads();

        // ---- phase 2: issue next tile's global loads ----
        const int kn = kt + BK;
        if (kn < kend) {
#pragma unroll
            for (int j = 0; j < 4; ++j)
                pa[j] = *reinterpret_cast<const float4*>(
                    &A[(size_t)(row0 + ar[j]) * NDIM + kn + aq[j]]);
#pragma unroll
            for (int kk = 0; kk < 16; ++kk)
                pb[kk] = B[(size_t)(kn + bkh + kk) * NDIM + col0 + bn];
        }

        // ---- phase 3: fragments + 16 MFMAs ----
        short8 af[4], bf[4];
#pragma unroll
        for (int m = 0; m < 4; ++m)
            af[m] = *reinterpret_cast<const short8*>(
                lAs + loff(wr + m * 16 + fr, kb));
#pragma unroll
        for (int n = 0; n < 4; ++n)
            bf[n] = *reinterpret_cast<const short8*>(
                lBs + loff(wc + n * 16 + fr, kb));
#pragma unroll
        for (int m = 0; m < 4; ++m)
#pragma unroll
            for (int n = 0; n < 4; ++n)
                acc[m][n] = __builtin_amdgcn_mfma_f32_16x16x32_bf16(
                    af[m], bf[n], acc[m][n], 0, 0, 0);
        __syncthreads();
    }

    // ---- epilogue: atomic accumulate (C pre-zeroed); mask row<=col ----
    // C/D layout: col=lane&15, row=(lane>>4)*4+reg
#pragma unroll
    for (int m = 0; m < 4; ++m) {
        const int rbase = row0 + wr + m * 16 + (lane >> 4) * 4;
#pragma unroll
        for (int n = 0; n < 4; ++n) {
            const int col = col0 + wc + n * 16 + fr;
#pragma unroll
            for (int r = 0; r < 4; ++r) {
                const int row = rbase + r;
                if (row <= col)
                    unsafeAtomicAdd(&C[(size_t)row * NDIM + col],
                                    acc[m][n][r]);
            }
        }
    }
}

extern "C" void kernel_launch(void* const* d_in, const int* in_sizes, int n_in,
                              void* d_out, int out_size, void* d_ws,
                              size_t ws_size, hipStream_t stream) {
    const float* A = (const float*)d_in[0];
    const float* B = (const float*)d_in[1];
    float* C = (float*)d_out;
    zero_c_kernel<<<dim3(2048), dim3(256), 0, stream>>>(C);
    trimm_split_kernel<<<dim3(NSUB), dim3(256), 0, stream>>>(A, B, C);
}

// Round 7
// 125.608 us; speedup vs baseline: 1.1846x; 1.1846x over previous
//
#include <hip/hip_runtime.h>
#include <hip/hip_bf16.h>

// C = triu( triu(A) @ triu(B) ), N=4096, fp32 in/out.
// Split-K bf16 MFMA, KSTEP=64, LDS double-buffer, ONE barrier per K-step.
// Each upper tile (bi,bj), L=bj-bi+1 k-tiles(128), split into ceil(L/8)
// sub-blocks (<=1024 k, <=16 steps) -> 1000 blocks. Kernel 1 zeroes C;
// kernel 2 accumulates partials with device fp32 atomics.

#define NDIM 4096
#define BM 128
#define BN 128
#define KSTEP 64
#define NBLK (NDIM / BM)                  // 32
#define NSUB 1000                         // sum over L of (33-L)*ceil(L/8)
#define LSTR 144                          // LDS row stride (128B data + 16B pad)
#define TILEB (BM * LSTR)                 // 18432 B per tile

typedef __attribute__((ext_vector_type(8))) short short8;
typedef __attribute__((ext_vector_type(4))) float f32x4;
typedef __attribute__((ext_vector_type(4))) float floatx4;

__device__ __forceinline__ int loff(int row, int kb) {
    return row * LSTR + kb;   // kb = byte offset within the 128B row data
}

// packed fp32x2 -> bf16x2 (RNE) -- compiler emits v_cvt_pk_bf16_f32
__device__ __forceinline__ unsigned pkbf(float a, float b) {
    __hip_bfloat162 h = __float22bfloat162_rn(make_float2(a, b));
    unsigned r;
    __builtin_memcpy(&r, &h, sizeof(r));
    return r;
}

__global__ __launch_bounds__(256) void zero_c_kernel(float* __restrict__ C) {
    const float4 z = make_float4(0.f, 0.f, 0.f, 0.f);
    const size_t total = (size_t)NDIM * NDIM / 4;
    for (size_t i = blockIdx.x * 256 + threadIdx.x; i < total;
         i += (size_t)gridDim.x * 256)
        reinterpret_cast<float4*>(C)[i] = z;
}

__global__ __launch_bounds__(256, 2) void trimm_split_kernel(
    const float* __restrict__ A, const float* __restrict__ B,
    float* __restrict__ C) {
    const int tid = threadIdx.x;

    // ---- decode sub-block id -> (bi, bj, chunk), longest-L first ----
    int bi, bj, ch;
    {
        int r = blockIdx.x;
        int L = NBLK;
        for (;;) {
            const int cpt = (L + 7) >> 3;
            const int cnt = (NBLK + 1 - L) * cpt;
            if (r < cnt) {
                bi = r / cpt;
                ch = r - bi * cpt;
                bj = bi + L - 1;
                break;
            }
            r -= cnt;
            --L;
        }
    }

    const int row0 = bi * BM;
    const int col0 = bj * BN;
    const int kstart = row0 + ch * 1024;
    const int kend = min(col0 + BN, kstart + 1024);

    __shared__ __align__(16) char lds[2][2 * TILEB];  // [buf][A | B]

    floatx4 acc[4][4];
    const floatx4 fz = {0.f, 0.f, 0.f, 0.f};
#pragma unroll
    for (int m = 0; m < 4; ++m)
#pragma unroll
        for (int n = 0; n < 4; ++n) acc[m][n] = fz;

    const int wv = tid >> 6;
    const int wr = (wv >> 1) * 64;
    const int wc = (wv & 1) * 64;
    const int lane = tid & 63;
    const int fr = lane & 15;
    const int kb = (lane >> 4) * 16;

    // A staging: thread owns 8 float4 chunks; f = tid+256j ->
    //   row = f>>4 (16 float4 per 64-float row), byte off = (f&15)*8
    int arow[4 * 2], abyt[4 * 2];
#pragma unroll
    for (int j = 0; j < 8; ++j) {
        const int f = tid + 256 * j;
        arow[j] = f >> 4;
        abyt[j] = (f & 15) * 8;
    }
    // B staging: thread owns cols cg..cg+3, k rows kq..kq+7
    const int cg = (tid & 31) * 4;
    const int kq = (tid >> 5) * 8;

    f32x4 pa[8], pb[8];

    // ---- helpers as lambdas (kept trivial; compile-time unrolled) ----
    auto load_tiles = [&](int kt) {
#pragma unroll
        for (int j = 0; j < 8; ++j)
            pa[j] = *reinterpret_cast<const f32x4*>(
                &A[(size_t)(row0 + arow[j]) * NDIM + kt + abyt[j] / 2]);
#pragma unroll
        for (int r = 0; r < 8; ++r)
            pb[r] = *reinterpret_cast<const f32x4*>(
                &B[(size_t)(kt + kq + r) * NDIM + col0 + cg]);
    };
    auto write_tiles = [&](char* base) {
        char* lA = base;
        char* lB = base + TILEB;
#pragma unroll
        for (int j = 0; j < 8; ++j) {
            uint2 w;
            w.x = pkbf(pa[j][0], pa[j][1]);
            w.y = pkbf(pa[j][2], pa[j][3]);
            *reinterpret_cast<uint2*>(lA + loff(arow[j], abyt[j])) = w;
        }
#pragma unroll
        for (int c = 0; c < 4; ++c) {
            uint4 w;
            w.x = pkbf(pb[0][c], pb[1][c]);
            w.y = pkbf(pb[2][c], pb[3][c]);
            w.z = pkbf(pb[4][c], pb[5][c]);
            w.w = pkbf(pb[6][c], pb[7][c]);
            *reinterpret_cast<uint4*>(lB + loff(cg + c, kq * 2)) = w;
        }
    };

    // ---- prologue: stage tile 0 into buffer 0 ----
    load_tiles(kstart);
    write_tiles(lds[0]);

    int cur = 0;
    for (int kt = kstart; kt < kend; kt += KSTEP) {
        __syncthreads();   // buf[cur] writes visible; vmcnt already 0

        const int kn = kt + KSTEP;
        if (kn < kend) load_tiles(kn);   // in flight under the MFMAs below

        char* lA = lds[cur];
        char* lB = lds[cur] + TILEB;
#pragma unroll
        for (int s = 0; s < 2; ++s) {    // two K=32 slices of the 64-k step
            short8 af[4], bf[4];
#pragma unroll
            for (int m = 0; m < 4; ++m)
                af[m] = *reinterpret_cast<const short8*>(
                    lA + loff(wr + m * 16 + fr, s * 64 + kb));
#pragma unroll
            for (int n = 0; n < 4; ++n)
                bf[n] = *reinterpret_cast<const short8*>(
                    lB + loff(wc + n * 16 + fr, s * 64 + kb));
#pragma unroll
            for (int m = 0; m < 4; ++m)
#pragma unroll
                for (int n = 0; n < 4; ++n)
                    acc[m][n] = __builtin_amdgcn_mfma_f32_16x16x32_bf16(
                        af[m], bf[n], acc[m][n], 0, 0, 0);
        }

        if (kn < kend) write_tiles(lds[cur ^ 1]);  // other buffer: no race
        cur ^= 1;
    }

    // ---- epilogue: atomic accumulate (C pre-zeroed); mask row<=col ----
    // C/D layout: col=lane&15, row=(lane>>4)*4+reg
#pragma unroll
    for (int m = 0; m < 4; ++m) {
        const int rbase = row0 + wr + m * 16 + (lane >> 4) * 4;
#pragma unroll
        for (int n = 0; n < 4; ++n) {
            const int col = col0 + wc + n * 16 + fr;
#pragma unroll
            for (int r = 0; r < 4; ++r) {
                const int row = rbase + r;
                if (row <= col)
                    unsafeAtomicAdd(&C[(size_t)row * NDIM + col],
                                    acc[m][n][r]);
            }
        }
    }
}

extern "C" void kernel_launch(void* const* d_in, const int* in_sizes, int n_in,
                              void* d_out, int out_size, void* d_ws,
                              size_t ws_size, hipStream_t stream) {
    const float* A = (const float*)d_in[0];
    const float* B = (const float*)d_in[1];
    float* C = (float*)d_out;
    zero_c_kernel<<<dim3(2048), dim3(256), 0, stream>>>(C);
    trimm_split_kernel<<<dim3(NSUB), dim3(256), 0, stream>>>(A, B, C);
}